// Round 1
// baseline (1035.300 us; speedup 1.0000x reference)
//
#include <hip/hip_runtime.h>
#include <hip/hip_bf16.h>

#define H_   2048
#define E_   8
#define T_   1024
#define TWOI 4096
#define I_   2048
#define ALPHA 1.702f
#define LIMIT 7.0f

typedef __attribute__((ext_vector_type(8))) short short8;
typedef __attribute__((ext_vector_type(4))) float f32x4;

__device__ __forceinline__ unsigned short f2bf(float f) {
    unsigned int u = __float_as_uint(f);
    u += 0x7fff + ((u >> 16) & 1);   // RTNE
    return (unsigned short)(u >> 16);
}

// ---------------------------------------------------------------- zero
__global__ void zero_kernel(float* __restrict__ out, int n, int* __restrict__ counts) {
    int i = blockIdx.x * blockDim.x + threadIdx.x;
    if (i < n) out[i] = 0.0f;
    if (i < E_) counts[i] = 0;
}

// ---------------------------------------------------------------- rmsnorm + router
__global__ __launch_bounds__(256) void rms_router(
    const float* __restrict__ x, const float* __restrict__ nw,
    const float* __restrict__ rw,
    unsigned short* __restrict__ tbf, int* __restrict__ counts,
    int* __restrict__ tlist, float* __restrict__ tw)
{
    int t = blockIdx.x;
    int tid = threadIdx.x;
    int wave = tid >> 6, lane = tid & 63;
    const float* xr = x + (size_t)t * H_;

    float4 v0 = *(const float4*)(xr + tid * 4);
    float4 v1 = *(const float4*)(xr + 1024 + tid * 4);
    float ss = v0.x*v0.x + v0.y*v0.y + v0.z*v0.z + v0.w*v0.w
             + v1.x*v1.x + v1.y*v1.y + v1.z*v1.z + v1.w*v1.w;
    #pragma unroll
    for (int s = 32; s; s >>= 1) ss += __shfl_xor(ss, s);

    __shared__ float red[4];
    __shared__ float wlog[4][8];
    if (lane == 0) red[wave] = ss;
    __syncthreads();
    float total = red[0] + red[1] + red[2] + red[3];
    float scale = rsqrtf(total * (1.0f / H_) + 1e-5f);

    float4 n0 = *(const float4*)(nw + tid * 4);
    float4 n1 = *(const float4*)(nw + 1024 + tid * 4);
    float tv[8];
    tv[0] = v0.x * scale * n0.x; tv[1] = v0.y * scale * n0.y;
    tv[2] = v0.z * scale * n0.z; tv[3] = v0.w * scale * n0.w;
    tv[4] = v1.x * scale * n1.x; tv[5] = v1.y * scale * n1.y;
    tv[6] = v1.z * scale * n1.z; tv[7] = v1.w * scale * n1.w;

    ushort4 o0 = make_ushort4(f2bf(tv[0]), f2bf(tv[1]), f2bf(tv[2]), f2bf(tv[3]));
    ushort4 o1 = make_ushort4(f2bf(tv[4]), f2bf(tv[5]), f2bf(tv[6]), f2bf(tv[7]));
    *(ushort4*)(tbf + (size_t)t * H_ + tid * 4) = o0;
    *(ushort4*)(tbf + (size_t)t * H_ + 1024 + tid * 4) = o1;

    float acc[E_];
    #pragma unroll
    for (int e = 0; e < E_; e++) {
        const float* r0 = rw + (size_t)e * H_ + tid * 4;
        float4 a = *(const float4*)r0;
        float4 b = *(const float4*)(r0 + 1024);
        acc[e] = tv[0]*a.x + tv[1]*a.y + tv[2]*a.z + tv[3]*a.w
               + tv[4]*b.x + tv[5]*b.y + tv[6]*b.z + tv[7]*b.w;
    }
    #pragma unroll
    for (int s = 32; s; s >>= 1)
        #pragma unroll
        for (int e = 0; e < E_; e++) acc[e] += __shfl_xor(acc[e], s);
    if (lane == 0)
        #pragma unroll
        for (int e = 0; e < E_; e++) wlog[wave][e] = acc[e];
    __syncthreads();

    if (tid == 0) {
        float lg[E_];
        #pragma unroll
        for (int e = 0; e < E_; e++)
            lg[e] = wlog[0][e] + wlog[1][e] + wlog[2][e] + wlog[3][e];
        int i0 = 0;
        #pragma unroll
        for (int e = 1; e < E_; e++) if (lg[e] > lg[i0]) i0 = e;
        int i1 = -1;
        #pragma unroll
        for (int e = 0; e < E_; e++) {
            if (e == i0) continue;
            if (i1 < 0 || lg[e] > lg[i1]) i1 = e;
        }
        float e1 = expf(lg[i1] - lg[i0]);
        float s = 1.0f + e1;
        float w0 = 1.0f / s, w1 = e1 / s;
        int p0 = atomicAdd(&counts[i0], 1);
        tlist[i0 * T_ + p0] = t; tw[i0 * T_ + p0] = w0;
        int p1 = atomicAdd(&counts[i1], 1);
        tlist[i1 * T_ + p1] = t; tw[i1 * T_ + p1] = w1;
    }
}

// ---------------------------------------------------------------- GU GEMM + swiglu
#define BK   32
#define LDSW 40   // 32 + 8 pad (bf16 elems)

__global__ __launch_bounds__(256) void gu_gemm(
    const unsigned short* __restrict__ tbf,
    const float* __restrict__ wgu,
    const int* __restrict__ counts, const int* __restrict__ tlist,
    unsigned short* __restrict__ act)
{
    int e = blockIdx.x >> 3;
    int mtile = blockIdx.x & 7;
    int cnt = counts[e];
    int m0 = mtile * 128;
    if (m0 >= cnt) return;
    int n0 = blockIdx.y * 128;

    __shared__ unsigned short As[128][LDSW];
    __shared__ unsigned short Bs[128][LDSW];   // transposed: [n][k]

    int tid = threadIdx.x;
    int lane = tid & 63, wave = tid >> 6;
    int wm = wave >> 1, wn = wave & 1;

    int arow[2], aq[2];
    const unsigned short* asrc[2];
    #pragma unroll
    for (int i = 0; i < 2; i++) {
        int c = tid + i * 256;
        arow[i] = c >> 2; aq[i] = c & 3;
        int gr = m0 + arow[i];
        asrc[i] = nullptr;
        if (gr < cnt) {
            int tok = tlist[e * T_ + gr];
            asrc[i] = tbf + (size_t)tok * H_ + aq[i] * 8;
        }
    }
    const float* bbase = wgu + (size_t)e * H_ * TWOI + n0;

    f32x4 acc[4][4];
    #pragma unroll
    for (int mi = 0; mi < 4; mi++)
        #pragma unroll
        for (int ni = 0; ni < 4; ni++) acc[mi][ni] = (f32x4){0.f, 0.f, 0.f, 0.f};

    for (int k0 = 0; k0 < H_; k0 += BK) {
        __syncthreads();
        #pragma unroll
        for (int i = 0; i < 2; i++) {
            uint4 v = make_uint4(0u, 0u, 0u, 0u);
            if (asrc[i]) v = *(const uint4*)(asrc[i] + k0);
            *(uint4*)(&As[arow[i]][aq[i] * 8]) = v;
        }
        #pragma unroll
        for (int j = 0; j < 4; j++) {
            int c = tid + j * 256;
            int kr = c >> 5, q = c & 31;
            float4 v = *(const float4*)(bbase + (size_t)(k0 + kr) * TWOI + q * 4);
            Bs[q * 4 + 0][kr] = f2bf(v.x);
            Bs[q * 4 + 1][kr] = f2bf(v.y);
            Bs[q * 4 + 2][kr] = f2bf(v.z);
            Bs[q * 4 + 3][kr] = f2bf(v.w);
        }
        __syncthreads();

        short8 a[4], b[4];
        int koff = (lane >> 4) * 8;
        #pragma unroll
        for (int mi = 0; mi < 4; mi++)
            a[mi] = *(const short8*)(&As[wm * 64 + mi * 16 + (lane & 15)][koff]);
        #pragma unroll
        for (int ni = 0; ni < 4; ni++)
            b[ni] = *(const short8*)(&Bs[wn * 64 + ni * 16 + (lane & 15)][koff]);
        #pragma unroll
        for (int mi = 0; mi < 4; mi++)
            #pragma unroll
            for (int ni = 0; ni < 4; ni++)
                acc[mi][ni] = __builtin_amdgcn_mfma_f32_16x16x32_bf16(a[mi], b[ni], acc[mi][ni], 0, 0, 0);
    }

    // epilogue: swiglu on column pairs (even=gate, odd=linear), write act bf16
    #pragma unroll
    for (int mi = 0; mi < 4; mi++) {
        #pragma unroll
        for (int ni = 0; ni < 4; ni++) {
            #pragma unroll
            for (int r = 0; r < 4; r++) {
                float v = acc[mi][ni][r];
                float p = __shfl_xor(v, 1);
                int rowe = wm * 64 + mi * 16 + (lane >> 4) * 4 + r;
                int grow = m0 + rowe;
                if (!(lane & 1) && grow < cnt) {
                    float glu = fminf(v, LIMIT);
                    float lin = fminf(fmaxf(p, -LIMIT), LIMIT);
                    float g = glu / (1.0f + __expf(-ALPHA * glu));
                    float a_ = g * (lin + 1.0f);
                    int col = n0 + wn * 64 + ni * 16 + (lane & 15);
                    act[((size_t)e * T_ + grow) * I_ + (col >> 1)] = f2bf(a_);
                }
            }
        }
    }
}

// ---------------------------------------------------------------- DOWN GEMM + scatter
__global__ __launch_bounds__(256) void down_gemm(
    const unsigned short* __restrict__ act,
    const float* __restrict__ wdn,
    const int* __restrict__ counts, const int* __restrict__ tlist,
    const float* __restrict__ tw, float* __restrict__ out)
{
    int e = blockIdx.x >> 3;
    int mtile = blockIdx.x & 7;
    int cnt = counts[e];
    int m0 = mtile * 128;
    if (m0 >= cnt) return;
    int n0 = blockIdx.y * 128;

    __shared__ unsigned short As[128][LDSW];
    __shared__ unsigned short Bs[128][LDSW];

    int tid = threadIdx.x;
    int lane = tid & 63, wave = tid >> 6;
    int wm = wave >> 1, wn = wave & 1;

    int arow[2], aq[2];
    const unsigned short* asrc[2];
    #pragma unroll
    for (int i = 0; i < 2; i++) {
        int c = tid + i * 256;
        arow[i] = c >> 2; aq[i] = c & 3;
        asrc[i] = act + ((size_t)e * T_ + m0 + arow[i]) * I_ + aq[i] * 8;
    }
    const float* bbase = wdn + (size_t)e * I_ * H_ + n0;

    f32x4 acc[4][4];
    #pragma unroll
    for (int mi = 0; mi < 4; mi++)
        #pragma unroll
        for (int ni = 0; ni < 4; ni++) acc[mi][ni] = (f32x4){0.f, 0.f, 0.f, 0.f};

    for (int k0 = 0; k0 < I_; k0 += BK) {
        __syncthreads();
        #pragma unroll
        for (int i = 0; i < 2; i++) {
            uint4 v = *(const uint4*)(asrc[i] + k0);
            *(uint4*)(&As[arow[i]][aq[i] * 8]) = v;
        }
        #pragma unroll
        for (int j = 0; j < 4; j++) {
            int c = tid + j * 256;
            int kr = c >> 5, q = c & 31;
            float4 v = *(const float4*)(bbase + (size_t)(k0 + kr) * H_ + q * 4);
            Bs[q * 4 + 0][kr] = f2bf(v.x);
            Bs[q * 4 + 1][kr] = f2bf(v.y);
            Bs[q * 4 + 2][kr] = f2bf(v.z);
            Bs[q * 4 + 3][kr] = f2bf(v.w);
        }
        __syncthreads();

        short8 a[4], b[4];
        int koff = (lane >> 4) * 8;
        #pragma unroll
        for (int mi = 0; mi < 4; mi++)
            a[mi] = *(const short8*)(&As[wm * 64 + mi * 16 + (lane & 15)][koff]);
        #pragma unroll
        for (int ni = 0; ni < 4; ni++)
            b[ni] = *(const short8*)(&Bs[wn * 64 + ni * 16 + (lane & 15)][koff]);
        #pragma unroll
        for (int mi = 0; mi < 4; mi++)
            #pragma unroll
            for (int ni = 0; ni < 4; ni++)
                acc[mi][ni] = __builtin_amdgcn_mfma_f32_16x16x32_bf16(a[mi], b[ni], acc[mi][ni], 0, 0, 0);
    }

    #pragma unroll
    for (int mi = 0; mi < 4; mi++) {
        #pragma unroll
        for (int ni = 0; ni < 4; ni++) {
            #pragma unroll
            for (int r = 0; r < 4; r++) {
                int rowe = wm * 64 + mi * 16 + (lane >> 4) * 4 + r;
                int grow = m0 + rowe;
                if (grow < cnt) {
                    int tok = tlist[e * T_ + grow];
                    float w = tw[e * T_ + grow];
                    int col = n0 + wn * 64 + ni * 16 + (lane & 15);
                    atomicAdd(&out[(size_t)tok * H_ + col], w * acc[mi][ni][r]);
                }
            }
        }
    }
}

// ---------------------------------------------------------------- launch
extern "C" void kernel_launch(void* const* d_in, const int* in_sizes, int n_in,
                              void* d_out, int out_size, void* d_ws, size_t ws_size,
                              hipStream_t stream)
{
    const float* x   = (const float*)d_in[0];
    const float* nw  = (const float*)d_in[1];
    const float* rw  = (const float*)d_in[2];
    const float* wgu = (const float*)d_in[3];
    const float* wdn = (const float*)d_in[4];
    float* out = (float*)d_out;

    char* ws = (char*)d_ws;
    unsigned short* tbf = (unsigned short*)ws;                       // 4 MB  [1024][2048] bf16
    unsigned short* act = (unsigned short*)(ws + (4u << 20));        // 32 MB [8][1024][2048] bf16
    int*   counts = (int*)(ws + (36u << 20));                        // 8 ints
    int*   tlist  = (int*)(ws + (36u << 20) + 256);                  // 8*1024 ints
    float* tw     = (float*)(ws + (36u << 20) + 256 + 8 * 1024 * 4); // 8*1024 floats

    int n = T_ * H_;
    zero_kernel<<<dim3((n + 255) / 256), 256, 0, stream>>>(out, n, counts);
    rms_router<<<dim3(T_), 256, 0, stream>>>(x, nw, rw, tbf, counts, tlist, tw);
    gu_gemm<<<dim3(64, 32), 256, 0, stream>>>(tbf, wgu, counts, tlist, act);
    down_gemm<<<dim3(64, 16), 256, 0, stream>>>(act, wdn, counts, tlist, tw, out);
}

// Round 2
// 613.519 us; speedup vs baseline: 1.6875x; 1.6875x over previous
//
#include <hip/hip_runtime.h>
#include <hip/hip_bf16.h>

#define H_   2048
#define E_   8
#define T_   1024
#define TWOI 4096
#define I_   2048
#define ALPHA 1.702f
#define LIMIT 7.0f

#define BM 128
#define BN 128
#define BKK 32
#define BPAD 130   // fp32 B-tile row length (conflict-free for frag reads)

typedef __attribute__((ext_vector_type(8))) short short8;
typedef __attribute__((ext_vector_type(4))) float f32x4;

#define AS3U(p) ((__attribute__((address_space(3))) unsigned int*)(p))
#define AS1U(p) ((const __attribute__((address_space(1))) unsigned int*)(p))

__device__ __forceinline__ unsigned short f2bf(float f) {
    unsigned int u = __float_as_uint(f);
    u += 0x7fff + ((u >> 16) & 1);   // RTNE
    return (unsigned short)(u >> 16);
}

__device__ __forceinline__ unsigned int cvtpk_bf16(float lo, float hi) {
    unsigned int r;
    asm("v_cvt_pk_bf16_f32 %0, %1, %2" : "=v"(r) : "v"(lo), "v"(hi));
    return r;
}

// ---------------------------------------------------------------- zero
__global__ void zero_kernel(float* __restrict__ out, int n, int* __restrict__ counts) {
    int i = blockIdx.x * blockDim.x + threadIdx.x;
    if (i < n) out[i] = 0.0f;
    if (i < E_) counts[i] = 0;
}

// ---------------------------------------------------------------- rmsnorm + router
__global__ __launch_bounds__(256) void rms_router(
    const float* __restrict__ x, const float* __restrict__ nw,
    const float* __restrict__ rw,
    unsigned short* __restrict__ tbf, int* __restrict__ counts,
    int* __restrict__ tlist, float* __restrict__ tw)
{
    int t = blockIdx.x;
    int tid = threadIdx.x;
    int wave = tid >> 6, lane = tid & 63;
    const float* xr = x + (size_t)t * H_;

    float4 v0 = *(const float4*)(xr + tid * 4);
    float4 v1 = *(const float4*)(xr + 1024 + tid * 4);
    float ss = v0.x*v0.x + v0.y*v0.y + v0.z*v0.z + v0.w*v0.w
             + v1.x*v1.x + v1.y*v1.y + v1.z*v1.z + v1.w*v1.w;
    #pragma unroll
    for (int s = 32; s; s >>= 1) ss += __shfl_xor(ss, s);

    __shared__ float red[4];
    __shared__ float wlog[4][8];
    if (lane == 0) red[wave] = ss;
    __syncthreads();
    float total = red[0] + red[1] + red[2] + red[3];
    float scale = rsqrtf(total * (1.0f / H_) + 1e-5f);

    float4 n0 = *(const float4*)(nw + tid * 4);
    float4 n1 = *(const float4*)(nw + 1024 + tid * 4);
    float tv[8];
    tv[0] = v0.x * scale * n0.x; tv[1] = v0.y * scale * n0.y;
    tv[2] = v0.z * scale * n0.z; tv[3] = v0.w * scale * n0.w;
    tv[4] = v1.x * scale * n1.x; tv[5] = v1.y * scale * n1.y;
    tv[6] = v1.z * scale * n1.z; tv[7] = v1.w * scale * n1.w;

    ushort4 o0 = make_ushort4(f2bf(tv[0]), f2bf(tv[1]), f2bf(tv[2]), f2bf(tv[3]));
    ushort4 o1 = make_ushort4(f2bf(tv[4]), f2bf(tv[5]), f2bf(tv[6]), f2bf(tv[7]));
    *(ushort4*)(tbf + (size_t)t * H_ + tid * 4) = o0;
    *(ushort4*)(tbf + (size_t)t * H_ + 1024 + tid * 4) = o1;

    float acc[E_];
    #pragma unroll
    for (int e = 0; e < E_; e++) {
        const float* r0 = rw + (size_t)e * H_ + tid * 4;
        float4 a = *(const float4*)r0;
        float4 b = *(const float4*)(r0 + 1024);
        acc[e] = tv[0]*a.x + tv[1]*a.y + tv[2]*a.z + tv[3]*a.w
               + tv[4]*b.x + tv[5]*b.y + tv[6]*b.z + tv[7]*b.w;
    }
    #pragma unroll
    for (int s = 32; s; s >>= 1)
        #pragma unroll
        for (int e = 0; e < E_; e++) acc[e] += __shfl_xor(acc[e], s);
    if (lane == 0)
        #pragma unroll
        for (int e = 0; e < E_; e++) wlog[wave][e] = acc[e];
    __syncthreads();

    if (tid == 0) {
        float lg[E_];
        #pragma unroll
        for (int e = 0; e < E_; e++)
            lg[e] = wlog[0][e] + wlog[1][e] + wlog[2][e] + wlog[3][e];
        int i0 = 0;
        #pragma unroll
        for (int e = 1; e < E_; e++) if (lg[e] > lg[i0]) i0 = e;
        int i1 = -1;
        #pragma unroll
        for (int e = 0; e < E_; e++) {
            if (e == i0) continue;
            if (i1 < 0 || lg[e] > lg[i1]) i1 = e;
        }
        float e1 = expf(lg[i1] - lg[i0]);
        float s = 1.0f + e1;
        float w0 = 1.0f / s, w1 = e1 / s;
        int p0 = atomicAdd(&counts[i0], 1);
        tlist[i0 * T_ + p0] = t; tw[i0 * T_ + p0] = w0;
        int p1 = atomicAdd(&counts[i1], 1);
        tlist[i1 * T_ + p1] = t; tw[i1 * T_ + p1] = w1;
    }
}

// ---------------------------------------------------------------- shared GEMM machinery
// compute one 64x64 wave-tile K-step from As (bf16 linear [BM][32]) and Bs (fp32 [32][BPAD])
__device__ __forceinline__ void compute_step(
    const unsigned short (*Asb)[BKK], const float (*Bsb)[BPAD],
    int wm, int wn, int lane, f32x4 acc[4][4])
{
    short8 a[4], b[4];
    int arow = wm * 64 + (lane & 15);
    int koff = (lane >> 4) * 8;
    #pragma unroll
    for (int mi = 0; mi < 4; mi++)
        a[mi] = *(const short8*)(&Asb[arow + mi * 16][koff]);
    int bcol = wn * 64 + (lane & 15);
    #pragma unroll
    for (int ni = 0; ni < 4; ni++) {
        const float* p = &Bsb[koff][bcol + ni * 16];
        union { unsigned int u[4]; short8 s; } bu;
        #pragma unroll
        for (int h = 0; h < 4; h++)
            bu.u[h] = cvtpk_bf16(p[(2 * h) * BPAD], p[(2 * h + 1) * BPAD]);
        b[ni] = bu.s;
    }
    #pragma unroll
    for (int mi = 0; mi < 4; mi++)
        #pragma unroll
        for (int ni = 0; ni < 4; ni++)
            acc[mi][ni] = __builtin_amdgcn_mfma_f32_16x16x32_bf16(a[mi], b[ni], acc[mi][ni], 0, 0, 0);
}

// ---------------------------------------------------------------- GU GEMM + swiglu
__global__ __launch_bounds__(256, 3) void gu_gemm(
    const unsigned short* __restrict__ tbf,
    const float* __restrict__ wgu,
    const int* __restrict__ counts, const int* __restrict__ tlist,
    unsigned short* __restrict__ act)
{
    int e = blockIdx.x >> 3;
    int mtile = blockIdx.x & 7;
    int cnt = counts[e];
    int m0 = mtile * BM;
    if (m0 >= cnt) return;
    int n0 = blockIdx.y * BN;

    __shared__ unsigned short As[2][BM][BKK];
    __shared__ float Bs[2][BKK][BPAD];

    int tid = threadIdx.x;
    int lane = tid & 63, wave = tid >> 6;
    int wm = wave >> 1, wn = wave & 1;

    // gathered A sources: lane l of wave-instr i covers row wave*32+i*16+(l>>2), k-quarter l&3
    const unsigned short* asrc[2];
    #pragma unroll
    for (int i = 0; i < 2; i++) {
        int row = wave * 32 + i * 16 + (lane >> 2);
        int gr = m0 + row;
        int tok = tlist[e * T_ + (gr < cnt ? gr : 0)];
        asrc[i] = tbf + (size_t)tok * H_ + (lane & 3) * 8;
    }
    const float* bbase = wgu + (size_t)e * H_ * TWOI + n0;

    f32x4 acc[4][4];
    #pragma unroll
    for (int mi = 0; mi < 4; mi++)
        #pragma unroll
        for (int ni = 0; ni < 4; ni++) acc[mi][ni] = (f32x4){0.f, 0.f, 0.f, 0.f};

    float4 breg[4];
    int krow[4];
    #pragma unroll
    for (int j = 0; j < 4; j++) krow[j] = (wave << 3) + (j << 1) + (lane >> 5);
    int bq = (lane & 31) << 2;

    // ---- prologue: stage tile 0 into buf 0
    #pragma unroll
    for (int i = 0; i < 2; i++)
        __builtin_amdgcn_global_load_lds(AS1U(asrc[i]), AS3U(&As[0][wave * 32 + i * 16][0]), 16, 0, 0);
    #pragma unroll
    for (int j = 0; j < 4; j++)
        breg[j] = *(const float4*)(bbase + (size_t)krow[j] * TWOI + bq);
    #pragma unroll
    for (int j = 0; j < 4; j++) {
        float* d = &Bs[0][krow[j]][bq];
        *(float2*)(d)     = make_float2(breg[j].x, breg[j].y);
        *(float2*)(d + 2) = make_float2(breg[j].z, breg[j].w);
    }
    asm volatile("s_waitcnt vmcnt(0)" ::: "memory");
    __syncthreads();

    // ---- main loop: compute tile t (buf t&1) while staging tile t+1 (buf ~t&1)
    for (int t = 0; t < 63; t++) {
        int cur = t & 1, nxt = cur ^ 1;
        int kn = (t + 1) * BKK;
        #pragma unroll
        for (int i = 0; i < 2; i++)
            __builtin_amdgcn_global_load_lds(AS1U(asrc[i] + kn), AS3U(&As[nxt][wave * 32 + i * 16][0]), 16, 0, 0);
        #pragma unroll
        for (int j = 0; j < 4; j++)
            breg[j] = *(const float4*)(bbase + (size_t)(kn + krow[j]) * TWOI + bq);

        compute_step(As[cur], Bs[cur], wm, wn, lane, acc);

        #pragma unroll
        for (int j = 0; j < 4; j++) {
            float* d = &Bs[nxt][krow[j]][bq];
            *(float2*)(d)     = make_float2(breg[j].x, breg[j].y);
            *(float2*)(d + 2) = make_float2(breg[j].z, breg[j].w);
        }
        asm volatile("s_waitcnt vmcnt(0)" ::: "memory");
        __syncthreads();
    }
    compute_step(As[1], Bs[1], wm, wn, lane, acc);

    // ---- epilogue: swiglu on column pairs (even=gate, odd=linear), write act bf16
    #pragma unroll
    for (int mi = 0; mi < 4; mi++) {
        #pragma unroll
        for (int ni = 0; ni < 4; ni++) {
            #pragma unroll
            for (int r = 0; r < 4; r++) {
                float v = acc[mi][ni][r];
                float p = __shfl_xor(v, 1);
                int rowe = wm * 64 + mi * 16 + (lane >> 4) * 4 + r;
                int grow = m0 + rowe;
                if (!(lane & 1) && grow < cnt) {
                    float glu = fminf(v, LIMIT);
                    float lin = fminf(fmaxf(p, -LIMIT), LIMIT);
                    float g = glu / (1.0f + __expf(-ALPHA * glu));
                    float a_ = g * (lin + 1.0f);
                    int col = n0 + wn * 64 + ni * 16 + (lane & 15);
                    act[((size_t)e * T_ + grow) * I_ + (col >> 1)] = f2bf(a_);
                }
            }
        }
    }
}

// ---------------------------------------------------------------- DOWN GEMM + scatter
__global__ __launch_bounds__(256, 3) void down_gemm(
    const unsigned short* __restrict__ act,
    const float* __restrict__ wdn,
    const int* __restrict__ counts, const int* __restrict__ tlist,
    const float* __restrict__ tw, float* __restrict__ out)
{
    int e = blockIdx.x >> 3;
    int mtile = blockIdx.x & 7;
    int cnt = counts[e];
    int m0 = mtile * BM;
    if (m0 >= cnt) return;
    int n0 = blockIdx.y * BN;

    __shared__ unsigned short As[2][BM][BKK];
    __shared__ float Bs[2][BKK][BPAD];

    int tid = threadIdx.x;
    int lane = tid & 63, wave = tid >> 6;
    int wm = wave >> 1, wn = wave & 1;

    const unsigned short* asrc[2];
    #pragma unroll
    for (int i = 0; i < 2; i++) {
        int row = wave * 32 + i * 16 + (lane >> 2);
        asrc[i] = act + ((size_t)e * T_ + m0 + row) * I_ + (lane & 3) * 8;
    }
    const float* bbase = wdn + (size_t)e * I_ * H_ + n0;

    f32x4 acc[4][4];
    #pragma unroll
    for (int mi = 0; mi < 4; mi++)
        #pragma unroll
        for (int ni = 0; ni < 4; ni++) acc[mi][ni] = (f32x4){0.f, 0.f, 0.f, 0.f};

    float4 breg[4];
    int krow[4];
    #pragma unroll
    for (int j = 0; j < 4; j++) krow[j] = (wave << 3) + (j << 1) + (lane >> 5);
    int bq = (lane & 31) << 2;

    #pragma unroll
    for (int i = 0; i < 2; i++)
        __builtin_amdgcn_global_load_lds(AS1U(asrc[i]), AS3U(&As[0][wave * 32 + i * 16][0]), 16, 0, 0);
    #pragma unroll
    for (int j = 0; j < 4; j++)
        breg[j] = *(const float4*)(bbase + (size_t)krow[j] * H_ + bq);
    #pragma unroll
    for (int j = 0; j < 4; j++) {
        float* d = &Bs[0][krow[j]][bq];
        *(float2*)(d)     = make_float2(breg[j].x, breg[j].y);
        *(float2*)(d + 2) = make_float2(breg[j].z, breg[j].w);
    }
    asm volatile("s_waitcnt vmcnt(0)" ::: "memory");
    __syncthreads();

    for (int t = 0; t < 63; t++) {
        int cur = t & 1, nxt = cur ^ 1;
        int kn = (t + 1) * BKK;
        #pragma unroll
        for (int i = 0; i < 2; i++)
            __builtin_amdgcn_global_load_lds(AS1U(asrc[i] + kn), AS3U(&As[nxt][wave * 32 + i * 16][0]), 16, 0, 0);
        #pragma unroll
        for (int j = 0; j < 4; j++)
            breg[j] = *(const float4*)(bbase + (size_t)(kn + krow[j]) * H_ + bq);

        compute_step(As[cur], Bs[cur], wm, wn, lane, acc);

        #pragma unroll
        for (int j = 0; j < 4; j++) {
            float* d = &Bs[nxt][krow[j]][bq];
            *(float2*)(d)     = make_float2(breg[j].x, breg[j].y);
            *(float2*)(d + 2) = make_float2(breg[j].z, breg[j].w);
        }
        asm volatile("s_waitcnt vmcnt(0)" ::: "memory");
        __syncthreads();
    }
    compute_step(As[1], Bs[1], wm, wn, lane, acc);

    #pragma unroll
    for (int mi = 0; mi < 4; mi++) {
        #pragma unroll
        for (int ni = 0; ni < 4; ni++) {
            #pragma unroll
            for (int r = 0; r < 4; r++) {
                int rowe = wm * 64 + mi * 16 + (lane >> 4) * 4 + r;
                int grow = m0 + rowe;
                if (grow < cnt) {
                    int tok = tlist[e * T_ + grow];
                    float w = tw[e * T_ + grow];
                    int col = n0 + wn * 64 + ni * 16 + (lane & 15);
                    atomicAdd(&out[(size_t)tok * H_ + col], w * acc[mi][ni][r]);
                }
            }
        }
    }
}

// ---------------------------------------------------------------- launch
extern "C" void kernel_launch(void* const* d_in, const int* in_sizes, int n_in,
                              void* d_out, int out_size, void* d_ws, size_t ws_size,
                              hipStream_t stream)
{
    const float* x   = (const float*)d_in[0];
    const float* nw  = (const float*)d_in[1];
    const float* rw  = (const float*)d_in[2];
    const float* wgu = (const float*)d_in[3];
    const float* wdn = (const float*)d_in[4];
    float* out = (float*)d_out;

    char* ws = (char*)d_ws;
    unsigned short* tbf = (unsigned short*)ws;                       // 4 MB  [1024][2048] bf16
    unsigned short* act = (unsigned short*)(ws + (4u << 20));        // 32 MB [8][1024][2048] bf16
    int*   counts = (int*)(ws + (36u << 20));                        // 8 ints
    int*   tlist  = (int*)(ws + (36u << 20) + 256);                  // 8*1024 ints
    float* tw     = (float*)(ws + (36u << 20) + 256 + 8 * 1024 * 4); // 8*1024 floats

    int n = T_ * H_;
    zero_kernel<<<dim3((n + 255) / 256), 256, 0, stream>>>(out, n, counts);
    rms_router<<<dim3(T_), 256, 0, stream>>>(x, nw, rw, tbf, counts, tlist, tw);
    gu_gemm<<<dim3(64, 32), 256, 0, stream>>>(tbf, wgu, counts, tlist, act);
    down_gemm<<<dim3(64, 16), 256, 0, stream>>>(act, wdn, counts, tlist, tw, out);
}

// Round 4
// 306.750 us; speedup vs baseline: 3.3751x; 2.0001x over previous
//
#include <hip/hip_runtime.h>
#include <hip/hip_bf16.h>

#define H_   2048
#define E_   8
#define T_   1024
#define TWOI 4096
#define I_   2048
#define ALPHA 1.702f
#define LIMIT 7.0f

#define BM 128
#define BN 128
#define BKK 32
#define BPAD 130   // fp32 B-tile row length (conflict-free for frag reads)

typedef __attribute__((ext_vector_type(8))) short short8;
typedef __attribute__((ext_vector_type(4))) float f32x4;

#define AS3U(p) ((__attribute__((address_space(3))) unsigned int*)(p))
#define AS1U(p) ((const __attribute__((address_space(1))) unsigned int*)(p))

__device__ __forceinline__ unsigned short f2bf(float f) {
    unsigned int u = __float_as_uint(f);
    u += 0x7fff + ((u >> 16) & 1);   // RTNE
    return (unsigned short)(u >> 16);
}

__device__ __forceinline__ unsigned int cvtpk_bf16(float lo, float hi) {
    unsigned int r;
    asm("v_cvt_pk_bf16_f32 %0, %1, %2" : "=v"(r) : "v"(lo), "v"(hi));
    return r;
}

// ---------------------------------------------------------------- zero
__global__ void zero_kernel(float* __restrict__ out, int n, int* __restrict__ counts) {
    int i = blockIdx.x * blockDim.x + threadIdx.x;
    if (i < n) out[i] = 0.0f;
    if (i < E_) counts[i] = 0;
}

// ---------------------------------------------------------------- rmsnorm + router
__global__ __launch_bounds__(256) void rms_router(
    const float* __restrict__ x, const float* __restrict__ nw,
    const float* __restrict__ rw,
    unsigned short* __restrict__ tbf, int* __restrict__ counts,
    int* __restrict__ tlist, float* __restrict__ tw)
{
    int t = blockIdx.x;
    int tid = threadIdx.x;
    int wave = tid >> 6, lane = tid & 63;
    const float* xr = x + (size_t)t * H_;

    float4 v0 = *(const float4*)(xr + tid * 4);
    float4 v1 = *(const float4*)(xr + 1024 + tid * 4);
    float ss = v0.x*v0.x + v0.y*v0.y + v0.z*v0.z + v0.w*v0.w
             + v1.x*v1.x + v1.y*v1.y + v1.z*v1.z + v1.w*v1.w;
    #pragma unroll
    for (int s = 32; s; s >>= 1) ss += __shfl_xor(ss, s);

    __shared__ float red[4];
    __shared__ float wlog[4][8];
    if (lane == 0) red[wave] = ss;
    __syncthreads();
    float total = red[0] + red[1] + red[2] + red[3];
    float scale = rsqrtf(total * (1.0f / H_) + 1e-5f);

    float4 n0 = *(const float4*)(nw + tid * 4);
    float4 n1 = *(const float4*)(nw + 1024 + tid * 4);
    float tv[8];
    tv[0] = v0.x * scale * n0.x; tv[1] = v0.y * scale * n0.y;
    tv[2] = v0.z * scale * n0.z; tv[3] = v0.w * scale * n0.w;
    tv[4] = v1.x * scale * n1.x; tv[5] = v1.y * scale * n1.y;
    tv[6] = v1.z * scale * n1.z; tv[7] = v1.w * scale * n1.w;

    ushort4 o0 = make_ushort4(f2bf(tv[0]), f2bf(tv[1]), f2bf(tv[2]), f2bf(tv[3]));
    ushort4 o1 = make_ushort4(f2bf(tv[4]), f2bf(tv[5]), f2bf(tv[6]), f2bf(tv[7]));
    *(ushort4*)(tbf + (size_t)t * H_ + tid * 4) = o0;
    *(ushort4*)(tbf + (size_t)t * H_ + 1024 + tid * 4) = o1;

    float acc[E_];
    #pragma unroll
    for (int e = 0; e < E_; e++) {
        const float* r0 = rw + (size_t)e * H_ + tid * 4;
        float4 a = *(const float4*)r0;
        float4 b = *(const float4*)(r0 + 1024);
        acc[e] = tv[0]*a.x + tv[1]*a.y + tv[2]*a.z + tv[3]*a.w
               + tv[4]*b.x + tv[5]*b.y + tv[6]*b.z + tv[7]*b.w;
    }
    #pragma unroll
    for (int s = 32; s; s >>= 1)
        #pragma unroll
        for (int e = 0; e < E_; e++) acc[e] += __shfl_xor(acc[e], s);
    if (lane == 0)
        #pragma unroll
        for (int e = 0; e < E_; e++) wlog[wave][e] = acc[e];
    __syncthreads();

    if (tid == 0) {
        float lg[E_];
        #pragma unroll
        for (int e = 0; e < E_; e++)
            lg[e] = wlog[0][e] + wlog[1][e] + wlog[2][e] + wlog[3][e];
        int i0 = 0;
        #pragma unroll
        for (int e = 1; e < E_; e++) if (lg[e] > lg[i0]) i0 = e;
        int i1 = -1;
        #pragma unroll
        for (int e = 0; e < E_; e++) {
            if (e == i0) continue;
            if (i1 < 0 || lg[e] > lg[i1]) i1 = e;
        }
        float e1 = expf(lg[i1] - lg[i0]);
        float s = 1.0f + e1;
        float w0 = 1.0f / s, w1 = e1 / s;
        int p0 = atomicAdd(&counts[i0], 1);
        tlist[i0 * T_ + p0] = t; tw[i0 * T_ + p0] = w0;
        int p1 = atomicAdd(&counts[i1], 1);
        tlist[i1 * T_ + p1] = t; tw[i1 * T_ + p1] = w1;
    }
}

// ---------------------------------------------------------------- shared GEMM machinery
__device__ __forceinline__ void compute_step(
    const unsigned short (*Asb)[BKK], const float (*Bsb)[BPAD],
    int wm, int wn, int lane, f32x4 acc[4][4])
{
    short8 a[4], b[4];
    int arow = wm * 64 + (lane & 15);
    int koff = (lane >> 4) * 8;
    #pragma unroll
    for (int mi = 0; mi < 4; mi++)
        a[mi] = *(const short8*)(&Asb[arow + mi * 16][koff]);
    int bcol = wn * 64 + (lane & 15);
    #pragma unroll
    for (int ni = 0; ni < 4; ni++) {
        const float* p = &Bsb[koff][bcol + ni * 16];
        union { unsigned int u[4]; short8 s; } bu;
        #pragma unroll
        for (int h = 0; h < 4; h++)
            bu.u[h] = cvtpk_bf16(p[(2 * h) * BPAD], p[(2 * h + 1) * BPAD]);
        b[ni] = bu.s;
    }
    #pragma unroll
    for (int mi = 0; mi < 4; mi++)
        #pragma unroll
        for (int ni = 0; ni < 4; ni++)
            acc[mi][ni] = __builtin_amdgcn_mfma_f32_16x16x32_bf16(a[mi], b[ni], acc[mi][ni], 0, 0, 0);
}

// 3-deep pipelined grouped-GEMM body shared by gu/down.
// asrc0/asrc1: per-lane A source addresses (gathered rows, 16B per lane per instr)
// bbase: expert weight panel base; ldb: weight row stride
#define GEMM_PIPELINE(ldb)                                                        \
    float4 r0[4], r1[4];                                                          \
    int c0 = 0, c1 = 1, c2 = 2;                                                   \
    /* prologue: tiles 0 and 1 */                                                 \
    __builtin_amdgcn_global_load_lds(AS1U(asrc0), AS3U(&As[0][wave * 32][0]), 16, 0, 0);        \
    __builtin_amdgcn_global_load_lds(AS1U(asrc1), AS3U(&As[0][wave * 32 + 16][0]), 16, 0, 0);   \
    _Pragma("unroll")                                                             \
    for (int j = 0; j < 4; j++) r0[j] = *(const float4*)(bbase + (size_t)(krow[j]) * (ldb) + bq); \
    __builtin_amdgcn_global_load_lds(AS1U(asrc0 + BKK), AS3U(&As[1][wave * 32][0]), 16, 0, 0);      \
    __builtin_amdgcn_global_load_lds(AS1U(asrc1 + BKK), AS3U(&As[1][wave * 32 + 16][0]), 16, 0, 0); \
    _Pragma("unroll")                                                             \
    for (int j = 0; j < 4; j++) r1[j] = *(const float4*)(bbase + (size_t)(BKK + krow[j]) * (ldb) + bq); \
    __builtin_amdgcn_sched_barrier(0);                                            \
    asm volatile("s_waitcnt vmcnt(6)" ::: "memory");                              \
    __builtin_amdgcn_sched_barrier(0);                                            \
    _Pragma("unroll")                                                             \
    for (int j = 0; j < 4; j++) {                                                 \
        float* d = &Bs[0][krow[j]][bq];                                           \
        *(float2*)(d)     = make_float2(r0[j].x, r0[j].y);                        \
        *(float2*)(d + 2) = make_float2(r0[j].z, r0[j].w);                        \
    }                                                                             \
    asm volatile("s_waitcnt lgkmcnt(0)" ::: "memory");                            \
    __builtin_amdgcn_sched_barrier(0);                                            \
    __builtin_amdgcn_s_barrier();                                                 \
    __builtin_amdgcn_sched_barrier(0);                                            \
    for (int t = 0; t < 62; t += 2) {                                             \
        int kk = (t + 2) * BKK;                                                   \
        __builtin_amdgcn_global_load_lds(AS1U(asrc0 + kk), AS3U(&As[c2][wave * 32][0]), 16, 0, 0);      \
        __builtin_amdgcn_global_load_lds(AS1U(asrc1 + kk), AS3U(&As[c2][wave * 32 + 16][0]), 16, 0, 0); \
        _Pragma("unroll")                                                         \
        for (int j = 0; j < 4; j++) r0[j] = *(const float4*)(bbase + (size_t)(kk + krow[j]) * (ldb) + bq); \
        compute_step(As[c0], Bs[c0], wm, wn, lane, acc);                          \
        __builtin_amdgcn_sched_barrier(0);                                        \
        asm volatile("s_waitcnt vmcnt(6)" ::: "memory");                          \
        __builtin_amdgcn_sched_barrier(0);                                        \
        _Pragma("unroll")                                                         \
        for (int j = 0; j < 4; j++) {                                             \
            float* d = &Bs[c1][krow[j]][bq];                                      \
            *(float2*)(d)     = make_float2(r1[j].x, r1[j].y);                    \
            *(float2*)(d + 2) = make_float2(r1[j].z, r1[j].w);                    \
        }                                                                         \
        asm volatile("s_waitcnt lgkmcnt(0)" ::: "memory");                        \
        __builtin_amdgcn_sched_barrier(0);                                        \
        __builtin_amdgcn_s_barrier();                                             \
        __builtin_amdgcn_sched_barrier(0);                                        \
        { int tmp = c0; c0 = c1; c1 = c2; c2 = tmp; }                             \
        kk = (t + 3) * BKK;                                                       \
        __builtin_amdgcn_global_load_lds(AS1U(asrc0 + kk), AS3U(&As[c2][wave * 32][0]), 16, 0, 0);      \
        __builtin_amdgcn_global_load_lds(AS1U(asrc1 + kk), AS3U(&As[c2][wave * 32 + 16][0]), 16, 0, 0); \
        _Pragma("unroll")                                                         \
        for (int j = 0; j < 4; j++) r1[j] = *(const float4*)(bbase + (size_t)(kk + krow[j]) * (ldb) + bq); \
        compute_step(As[c0], Bs[c0], wm, wn, lane, acc);                          \
        __builtin_amdgcn_sched_barrier(0);                                        \
        asm volatile("s_waitcnt vmcnt(6)" ::: "memory");                          \
        __builtin_amdgcn_sched_barrier(0);                                        \
        _Pragma("unroll")                                                         \
        for (int j = 0; j < 4; j++) {                                             \
            float* d = &Bs[c1][krow[j]][bq];                                      \
            *(float2*)(d)     = make_float2(r0[j].x, r0[j].y);                    \
            *(float2*)(d + 2) = make_float2(r0[j].z, r0[j].w);                    \
        }                                                                         \
        asm volatile("s_waitcnt lgkmcnt(0)" ::: "memory");                        \
        __builtin_amdgcn_sched_barrier(0);                                        \
        __builtin_amdgcn_s_barrier();                                             \
        __builtin_amdgcn_sched_barrier(0);                                        \
        { int tmp = c0; c0 = c1; c1 = c2; c2 = tmp; }                             \
    }                                                                             \
    /* t = 62 */                                                                  \
    compute_step(As[c0], Bs[c0], wm, wn, lane, acc);                              \
    __builtin_amdgcn_sched_barrier(0);                                            \
    asm volatile("s_waitcnt vmcnt(0)" ::: "memory");                              \
    __builtin_amdgcn_sched_barrier(0);                                            \
    _Pragma("unroll")                                                             \
    for (int j = 0; j < 4; j++) {                                                 \
        float* d = &Bs[c1][krow[j]][bq];                                          \
        *(float2*)(d)     = make_float2(r1[j].x, r1[j].y);                        \
        *(float2*)(d + 2) = make_float2(r1[j].z, r1[j].w);                        \
    }                                                                             \
    asm volatile("s_waitcnt lgkmcnt(0)" ::: "memory");                            \
    __builtin_amdgcn_sched_barrier(0);                                            \
    __builtin_amdgcn_s_barrier();                                                 \
    __builtin_amdgcn_sched_barrier(0);                                            \
    { int tmp = c0; c0 = c1; c1 = c2; c2 = tmp; }                                 \
    /* t = 63 */                                                                  \
    compute_step(As[c0], Bs[c0], wm, wn, lane, acc);

// ---------------------------------------------------------------- GU GEMM + swiglu
__global__ __launch_bounds__(256, 2) void gu_gemm(
    const unsigned short* __restrict__ tbf,
    const float* __restrict__ wgu,
    const int* __restrict__ counts, const int* __restrict__ tlist,
    unsigned short* __restrict__ act)
{
    // XCD swizzle: expert e -> XCD e (grid 2048, 256 blocks/expert)
    int bid = blockIdx.x;
    int swz = (bid & 7) * 256 + (bid >> 3);
    int e = swz >> 8;
    int rem = swz & 255;
    int mtile = rem & 7;
    int n0 = (rem >> 3) * BN;

    int cnt = counts[e];
    int m0 = mtile * BM;
    if (m0 >= cnt) return;

    __shared__ unsigned short As[3][BM][BKK];
    __shared__ float Bs[3][BKK][BPAD];

    int tid = threadIdx.x;
    int lane = tid & 63, wave = tid >> 6;
    int wm = wave >> 1, wn = wave & 1;

    int row0 = wave * 32 + (lane >> 2);
    int gr0 = m0 + row0, gr1 = gr0 + 16;
    int tok0 = tlist[e * T_ + (gr0 < cnt ? gr0 : 0)];
    int tok1 = tlist[e * T_ + (gr1 < cnt ? gr1 : 0)];
    const unsigned short* asrc0 = tbf + (size_t)tok0 * H_ + (lane & 3) * 8;
    const unsigned short* asrc1 = tbf + (size_t)tok1 * H_ + (lane & 3) * 8;
    const float* bbase = wgu + (size_t)e * H_ * TWOI + n0;

    f32x4 acc[4][4];
    #pragma unroll
    for (int mi = 0; mi < 4; mi++)
        #pragma unroll
        for (int ni = 0; ni < 4; ni++) acc[mi][ni] = (f32x4){0.f, 0.f, 0.f, 0.f};

    int krow[4];
    #pragma unroll
    for (int j = 0; j < 4; j++) krow[j] = (wave << 3) + (j << 1) + (lane >> 5);
    int bq = (lane & 31) << 2;

    GEMM_PIPELINE(TWOI)

    // epilogue: swiglu on column pairs (even=gate, odd=linear), write act bf16
    #pragma unroll
    for (int mi = 0; mi < 4; mi++) {
        #pragma unroll
        for (int ni = 0; ni < 4; ni++) {
            #pragma unroll
            for (int r = 0; r < 4; r++) {
                float v = acc[mi][ni][r];
                float p = __shfl_xor(v, 1);
                int rowe = wm * 64 + mi * 16 + (lane >> 4) * 4 + r;
                int grow = m0 + rowe;
                if (!(lane & 1) && grow < cnt) {
                    float glu = fminf(v, LIMIT);
                    float lin = fminf(fmaxf(p, -LIMIT), LIMIT);
                    float g = glu / (1.0f + __expf(-ALPHA * glu));
                    float a_ = g * (lin + 1.0f);
                    int col = n0 + wn * 64 + ni * 16 + (lane & 15);
                    act[((size_t)e * T_ + grow) * I_ + (col >> 1)] = f2bf(a_);
                }
            }
        }
    }
}

// ---------------------------------------------------------------- DOWN GEMM + scatter
__global__ __launch_bounds__(256, 2) void down_gemm(
    const unsigned short* __restrict__ act,
    const float* __restrict__ wdn,
    const int* __restrict__ counts, const int* __restrict__ tlist,
    const float* __restrict__ tw, float* __restrict__ out)
{
    // XCD swizzle: expert e -> XCD e (grid 1024, 128 blocks/expert)
    int bid = blockIdx.x;
    int swz = (bid & 7) * 128 + (bid >> 3);
    int e = swz >> 7;
    int rem = swz & 127;
    int mtile = rem & 7;
    int n0 = (rem >> 3) * BN;

    int cnt = counts[e];
    int m0 = mtile * BM;
    if (m0 >= cnt) return;

    __shared__ unsigned short As[3][BM][BKK];
    __shared__ float Bs[3][BKK][BPAD];

    int tid = threadIdx.x;
    int lane = tid & 63, wave = tid >> 6;
    int wm = wave >> 1, wn = wave & 1;

    int row0 = wave * 32 + (lane >> 2);
    const unsigned short* asrc0 = act + ((size_t)e * T_ + m0 + row0) * I_ + (lane & 3) * 8;
    const unsigned short* asrc1 = asrc0 + (size_t)16 * I_;
    const float* bbase = wdn + (size_t)e * I_ * H_ + n0;

    f32x4 acc[4][4];
    #pragma unroll
    for (int mi = 0; mi < 4; mi++)
        #pragma unroll
        for (int ni = 0; ni < 4; ni++) acc[mi][ni] = (f32x4){0.f, 0.f, 0.f, 0.f};

    int krow[4];
    #pragma unroll
    for (int j = 0; j < 4; j++) krow[j] = (wave << 3) + (j << 1) + (lane >> 5);
    int bq = (lane & 31) << 2;

    GEMM_PIPELINE(H_)

    #pragma unroll
    for (int mi = 0; mi < 4; mi++) {
        #pragma unroll
        for (int ni = 0; ni < 4; ni++) {
            #pragma unroll
            for (int r = 0; r < 4; r++) {
                int rowe = wm * 64 + mi * 16 + (lane >> 4) * 4 + r;
                int grow = m0 + rowe;
                if (grow < cnt) {
                    int tok = tlist[e * T_ + grow];
                    float w = tw[e * T_ + grow];
                    int col = n0 + wn * 64 + ni * 16 + (lane & 15);
                    atomicAdd(&out[(size_t)tok * H_ + col], w * acc[mi][ni][r]);
                }
            }
        }
    }
}

// ---------------------------------------------------------------- launch
extern "C" void kernel_launch(void* const* d_in, const int* in_sizes, int n_in,
                              void* d_out, int out_size, void* d_ws, size_t ws_size,
                              hipStream_t stream)
{
    const float* x   = (const float*)d_in[0];
    const float* nw  = (const float*)d_in[1];
    const float* rw  = (const float*)d_in[2];
    const float* wgu = (const float*)d_in[3];
    const float* wdn = (const float*)d_in[4];
    float* out = (float*)d_out;

    char* ws = (char*)d_ws;
    unsigned short* tbf = (unsigned short*)ws;                       // 4 MB  [1024][2048] bf16
    unsigned short* act = (unsigned short*)(ws + (4u << 20));        // 32 MB [8][1024][2048] bf16
    int*   counts = (int*)(ws + (36u << 20));                        // 8 ints
    int*   tlist  = (int*)(ws + (36u << 20) + 256);                  // 8*1024 ints
    float* tw     = (float*)(ws + (36u << 20) + 256 + 8 * 1024 * 4); // 8*1024 floats

    int n = T_ * H_;
    zero_kernel<<<dim3((n + 255) / 256), 256, 0, stream>>>(out, n, counts);
    rms_router<<<dim3(T_), 256, 0, stream>>>(x, nw, rw, tbf, counts, tlist, tw);
    gu_gemm<<<dim3(2048), 256, 0, stream>>>(tbf, wgu, counts, tlist, act);
    down_gemm<<<dim3(1024), 256, 0, stream>>>(act, wdn, counts, tlist, tw, out);
}